// Round 6
// baseline (259.477 us; speedup 1.0000x reference)
//
#include <hip/hip_runtime.h>
#include <stdint.h>

#define BTOT   4096
#define NGRP   8
#define DMODEL 1024
#define HIDDEN 2048
#define ABIN   256

typedef short bf16x8 __attribute__((ext_vector_type(8)));
typedef float f32x4  __attribute__((ext_vector_type(4)));

__device__ __forceinline__ ushort f2bf(float f) {
    union { float f; uint32_t u; } v; v.f = f;
    return (ushort)((v.u + 0x7FFFu + ((v.u >> 16) & 1u)) >> 16);
}

__device__ __forceinline__ void gl_lds16(const ushort* g, ushort* l) {
    __builtin_amdgcn_global_load_lds(
        (const __attribute__((address_space(1))) uint32_t*)g,
        (__attribute__((address_space(3))) uint32_t*)l,
        16, 0, 0);
}

// ---- W[n][K][N] f32 -> Wt[n][N][K] bf16 ----
__global__ void transpose_w(const float* __restrict__ W, ushort* __restrict__ Wt,
                            int K, int N)
{
    __shared__ float tl[32][33];
    const int n  = blockIdx.y;
    const int nt = blockIdx.x % (N / 32);
    const int kt = blockIdx.x / (N / 32);
    const float* Wn  = W  + (size_t)n * K * N;
    ushort*      Wtn = Wt + (size_t)n * N * K;
    const int tx = threadIdx.x & 31, ty = threadIdx.x >> 5;
#pragma unroll
    for (int j = 0; j < 4; j++)
        tl[ty + 8 * j][tx] = Wn[(size_t)(kt * 32 + ty + 8 * j) * N + nt * 32 + tx];
    __syncthreads();
#pragma unroll
    for (int j = 0; j < 4; j++) {
        const int r = ty + 8 * j;
        Wtn[(size_t)(nt * 32 + r) * K + kt * 32 + tx] = f2bf(tl[tx][r]);
    }
}

// ---- x[cb+r][n][d] f32 -> xb[n][r][d] bf16 ----
__global__ void conv_x(const float* __restrict__ x, ushort* __restrict__ xb,
                       int CH, int cb)
{
    const int flat = blockIdx.x * 256 + threadIdx.x;
    const int d8 = flat & 127;
    const int rem = flat >> 7;
    const int n = rem & 7;
    const int r = rem >> 3;
    const float* src = x + ((size_t)(cb + r) * NGRP + n) * DMODEL + d8 * 8;
    float4 v0 = *(const float4*)(src);
    float4 v1 = *(const float4*)(src + 4);
    bf16x8 p;
    p[0] = (short)f2bf(v0.x); p[1] = (short)f2bf(v0.y);
    p[2] = (short)f2bf(v0.z); p[3] = (short)f2bf(v0.w);
    p[4] = (short)f2bf(v1.x); p[5] = (short)f2bf(v1.y);
    p[6] = (short)f2bf(v1.z); p[7] = (short)f2bf(v1.w);
    *(bf16x8*)(xb + ((size_t)n * CH + r) * DMODEL + d8 * 8) = p;
}

// region(buf,op,half,ks): 128 rows x 32 k bf16 = 8 KiB, swizzled granules
#define REGN(buf,op,half,ks) (sm + ((((buf)*2+(op))*2+(half))*2+(ks))*4096)

template<int MH>
__device__ __forceinline__ void mma_q(f32x4 (&acc)[8][4], const bf16x8 (&af)[4],
                                      const bf16x8 (&bv)[4])
{
#pragma unroll
    for (int m4 = 0; m4 < 4; ++m4)
#pragma unroll
        for (int nf = 0; nf < 4; ++nf)
            acc[MH * 4 + m4][nf] = __builtin_amdgcn_mfma_f32_16x16x32_bf16(
                af[m4], bv[nf], acc[MH * 4 + m4][nf], 0, 0, 0);
}

// ---- 256x256 GEMM1, uniform distance-2 fragment pipeline ----
__global__ __launch_bounds__(512, 2)
void gemm8_1(const ushort* __restrict__ A, const ushort* __restrict__ Bt,
             const float* __restrict__ bias, ushort* __restrict__ h, int CH)
{
    constexpr int K = DMODEL, NDIM = HIDDEN, KT = K / 64;
    const int MT = CH >> 8, NT = NDIM >> 8;     // NT = 8
    extern __shared__ ushort sm[];

    // XCD-aware swizzle (nwg % 8 == 0 by construction)
    const int nwg = gridDim.x;
    const int bid = blockIdx.x;
    const int swz = (bid & 7) * (nwg >> 3) + (bid >> 3);
    const int n   = swz / (MT * NT);
    const int rem = swz - n * (MT * NT);
    const int mt  = rem / NT;
    const int nt  = rem - mt * NT;

    const int tid = threadIdx.x;
    const int l = tid & 63, wid = tid >> 6;
    const int wr = wid >> 2, wc = wid & 3, wc2 = wc >> 1;
    const int lq = l >> 4, lr = l & 15;

    const ushort* Ab = A  + ((size_t)n * CH   + (size_t)mt * 256) * K;
    const ushort* Bb = Bt + ((size_t)n * NDIM + (size_t)nt * 256) * K;

    // stage map: LDS linear granule tid holds global granule (srow, sseg)
    const int srow = tid >> 2;
    const int sseg = (tid & 3) ^ ((tid >> 3) & 3);

    auto stageA = [&](int b, int T, int ks) {
        const size_t kofs = (size_t)T * 64 + ks * 32 + sseg * 8;
        gl_lds16(Ab + (size_t)srow * K + kofs,         REGN(b, 0, 0, ks) + tid * 8);
        gl_lds16(Ab + (size_t)(128 + srow) * K + kofs, REGN(b, 0, 1, ks) + tid * 8);
    };
    auto stageB = [&](int b, int T, int ks) {
        const size_t kofs = (size_t)T * 64 + ks * 32 + sseg * 8;
        gl_lds16(Bb + (size_t)srow * K + kofs,         REGN(b, 1, 0, ks) + tid * 8);
        gl_lds16(Bb + (size_t)(128 + srow) * K + kofs, REGN(b, 1, 1, ks) + tid * 8);
    };
    auto ldA = [&](bf16x8 (&af)[4], int b, int kk, int mh) {
#pragma unroll
        for (int m4 = 0; m4 < 4; ++m4) {
            const int rh = mh * 64 + m4 * 16 + lr;
            af[m4] = *(const bf16x8*)(REGN(b, 0, wr, kk) + rh * 32 + (lq ^ ((rh >> 1) & 3)) * 8);
        }
    };
    auto ldB = [&](bf16x8 (&bv)[4], int b, int kk) {
#pragma unroll
        for (int nf = 0; nf < 4; ++nf) {
            const int rb = (wc & 1) * 64 + nf * 16 + lr;
            bv[nf] = *(const bf16x8*)(REGN(b, 1, wc2, kk) + rb * 32 + (lq ^ ((rb >> 1) & 3)) * 8);
        }
    };

    f32x4 acc[8][4];
#pragma unroll
    for (int i = 0; i < 8; ++i)
#pragma unroll
        for (int j = 0; j < 4; ++j) acc[i][j] = (f32x4){0.f, 0.f, 0.f, 0.f};

    // prologue: stage tile0 fully, drain, barrier, pre-issue reads for P0,P1
    stageA(0, 0, 0); stageB(0, 0, 0);       // kk0 tile0 (4 loads)
    stageA(0, 0, 1); stageB(0, 0, 1);       // kk1 tile0 (4 loads)
    asm volatile("s_waitcnt vmcnt(0)" ::: "memory");
    __builtin_amdgcn_s_barrier();

    bf16x8 a0[4], a1[4], a2[4], a3[4], bE[4], bO[4];
    ldA(a0, 0, 0, 0); ldB(bE, 0, 0);        // for (0,P0): 8 reads
    ldA(a1, 0, 0, 1);                       // for (0,P1): 4 reads

    for (int g = 0; g < KT; ++g) {
        const int c = g & 1;
        const bool ns = (g + 1 < KT);

        // P0: mma (kk0,mh0)=a0,bE; stage kk0(g+1); reads for P2 (a2,bO)
        if (ns) { stageA(c ^ 1, g + 1, 0); stageB(c ^ 1, g + 1, 0); }
        ldA(a2, c, 1, 0); ldB(bO, c, 1);
        asm volatile("s_waitcnt lgkmcnt(12)" ::: "memory");
        __builtin_amdgcn_sched_barrier(0);
        __builtin_amdgcn_s_setprio(1);
        mma_q<0>(acc, a0, bE);
        __builtin_amdgcn_s_setprio(0);
        __builtin_amdgcn_s_barrier();

        // P1: mma (kk0,mh1)=a1,bE; reads for P3 (a3); gate kk0(g+1)
        ldA(a3, c, 1, 1);
        asm volatile("s_waitcnt lgkmcnt(12)" ::: "memory");
        __builtin_amdgcn_sched_barrier(0);
        __builtin_amdgcn_s_setprio(1);
        mma_q<1>(acc, a1, bE);
        __builtin_amdgcn_s_setprio(0);
        if (ns) asm volatile("s_waitcnt vmcnt(0)" ::: "memory");
        __builtin_amdgcn_s_barrier();

        // P2: mma (kk1,mh0)=a2,bO; stage kk1(g+1); reads for next-P0 (a0,bE)
        if (ns) {
            stageA(c ^ 1, g + 1, 1); stageB(c ^ 1, g + 1, 1);
            ldA(a0, c ^ 1, 0, 0); ldB(bE, c ^ 1, 0);
            asm volatile("s_waitcnt lgkmcnt(12)" ::: "memory");
        } else {
            asm volatile("s_waitcnt lgkmcnt(4)" ::: "memory");
        }
        __builtin_amdgcn_sched_barrier(0);
        __builtin_amdgcn_s_setprio(1);
        mma_q<0>(acc, a2, bO);
        __builtin_amdgcn_s_setprio(0);
        __builtin_amdgcn_s_barrier();

        // P3: mma (kk1,mh1)=a3,bO; reads for next-P1 (a1); gate kk1(g+1)
        if (ns) {
            ldA(a1, c ^ 1, 0, 1);
            asm volatile("s_waitcnt lgkmcnt(12)" ::: "memory");
        } else {
            asm volatile("s_waitcnt lgkmcnt(0)" ::: "memory");
        }
        __builtin_amdgcn_sched_barrier(0);
        __builtin_amdgcn_s_setprio(1);
        mma_q<1>(acc, a3, bO);
        __builtin_amdgcn_s_setprio(0);
        if (ns) asm volatile("s_waitcnt vmcnt(0)" ::: "memory");
        __builtin_amdgcn_s_barrier();
    }

    __builtin_amdgcn_sched_barrier(0);

    // epilogue: bias + relu + bf16 store (row-contiguous 128 B segments)
    float bias4[4];
#pragma unroll
    for (int nf = 0; nf < 4; ++nf)
        bias4[nf] = bias[(size_t)n * NDIM + nt * 256 + wc * 64 + nf * 16 + lr];
#pragma unroll
    for (int m = 0; m < 8; ++m) {
#pragma unroll
        for (int r = 0; r < 4; ++r) {
            const int row = mt * 256 + wr * 128 + m * 16 + lq * 4 + r;
            ushort* dst = h + ((size_t)n * CH + row) * HIDDEN + nt * 256 + wc * 64 + lr;
#pragma unroll
            for (int nf = 0; nf < 4; ++nf)
                dst[nf * 16] = f2bf(fmaxf(acc[m][nf][r] + bias4[nf], 0.f));
        }
    }
}

// ---- GEMM2 (m97 128^2 structure, 2-way swizzled LDS): out = h @ W2t^T + b2 ----
__global__ __launch_bounds__(256, 2)
void gemm2(const ushort* __restrict__ A, const ushort* __restrict__ Bt,
           const float* __restrict__ bias, float* __restrict__ outp,
           int CH, int cb)
{
    constexpr int K = HIDDEN, NDIM = ABIN, NT = NDIM / 128, BK = 64;
    __shared__ __align__(16) ushort As[128 * BK];
    __shared__ __align__(16) ushort Bs[128 * BK];

    const int n  = blockIdx.y;
    const int mt = blockIdx.x / NT;
    const int nt = blockIdx.x % NT;

    const ushort* Ab = A  + ((size_t)n * CH   + mt * 128) * K;
    const ushort* Bb = Bt + ((size_t)n * NDIM + nt * 128) * K;

    const int t = threadIdx.x, l = t & 63, w = t >> 6;
    const int wr = w >> 1, wc = w & 1;
    const int lq = l >> 4, lr = l & 15;

    f32x4 acc[4][4];
#pragma unroll
    for (int i = 0; i < 4; i++)
#pragma unroll
        for (int j = 0; j < 4; j++) acc[i][j] = (f32x4){0.f, 0.f, 0.f, 0.f};

    for (int ki = 0; ki < K / BK; ++ki) {
        const ushort* Ak = Ab + ki * BK;
        const ushort* Bk = Bb + ki * BK;
        __syncthreads();
#pragma unroll
        for (int i = 0; i < 4; i++) {
            const int flat = t + 256 * i;
            const int row = flat >> 3;
            const int seg = (flat & 7) ^ (row & 7);     // both-sides swizzle
            gl_lds16(Ak + (size_t)row * K + seg * 8, (ushort*)As + flat * 8);
            gl_lds16(Bk + (size_t)row * K + seg * 8, (ushort*)Bs + flat * 8);
        }
        __syncthreads();

#pragma unroll
        for (int kk = 0; kk < 2; kk++) {
            bf16x8 af[4], bf[4];
#pragma unroll
            for (int m = 0; m < 4; m++) {
                const int row = wr * 64 + m * 16 + lr;
                af[m] = *(const bf16x8*)&As[row * BK + ((kk * 4 + lq) ^ (row & 7)) * 8];
            }
#pragma unroll
            for (int nf = 0; nf < 4; nf++) {
                const int row = wc * 64 + nf * 16 + lr;
                bf[nf] = *(const bf16x8*)&Bs[row * BK + ((kk * 4 + lq) ^ (row & 7)) * 8];
            }
#pragma unroll
            for (int m = 0; m < 4; m++)
#pragma unroll
                for (int nf = 0; nf < 4; nf++)
                    acc[m][nf] = __builtin_amdgcn_mfma_f32_16x16x32_bf16(af[m], bf[nf], acc[m][nf], 0, 0, 0);
        }
    }

#pragma unroll
    for (int nf = 0; nf < 4; nf++) {
        const int colg = nt * 128 + wc * 64 + nf * 16 + lr;
        const float bv = bias[(size_t)n * NDIM + colg];
#pragma unroll
        for (int m = 0; m < 4; m++) {
#pragma unroll
            for (int r = 0; r < 4; r++) {
                const int row = mt * 128 + wr * 64 + m * 16 + lq * 4 + r;
                outp[((size_t)(cb + row) * NGRP + n) * ABIN + colg] = acc[m][nf][r] + bv;
            }
        }
    }
}

extern "C" void kernel_launch(void* const* d_in, const int* in_sizes, int n_in,
                              void* d_out, int out_size, void* d_ws, size_t ws_size,
                              hipStream_t stream)
{
    const float* x  = (const float*)d_in[0];
    const float* W1 = (const float*)d_in[1];
    const float* b1 = (const float*)d_in[2];
    const float* W2 = (const float*)d_in[3];
    const float* b2 = (const float*)d_in[4];

    hipFuncSetAttribute((const void*)gemm8_1,
                        hipFuncAttributeMaxDynamicSharedMemorySize, 131072);

    ushort* W1t = (ushort*)d_ws;                              // [8][2048][1024]
    ushort* W2t = W1t + (size_t)NGRP * HIDDEN * DMODEL;       // [8][256][2048]
    ushort* xb  = W2t + (size_t)NGRP * ABIN * HIDDEN;
    const size_t fixed = ((size_t)NGRP * HIDDEN * DMODEL + (size_t)NGRP * ABIN * HIDDEN) * 2;

    int CH = 4096;
    while (CH > 256 && fixed + (size_t)CH * (NGRP * (DMODEL + HIDDEN) * 2) > ws_size) CH >>= 1;
    ushort* h = xb + (size_t)NGRP * CH * DMODEL;

    {
        dim3 g1((DMODEL / 32) * (HIDDEN / 32), NGRP);
        transpose_w<<<g1, 256, 0, stream>>>(W1, W1t, DMODEL, HIDDEN);
        dim3 g2((HIDDEN / 32) * (ABIN / 32), NGRP);
        transpose_w<<<g2, 256, 0, stream>>>(W2, W2t, HIDDEN, ABIN);
    }

    for (int cb = 0; cb < BTOT; cb += CH) {
        conv_x<<<CH * 4, 256, 0, stream>>>(x, xb, CH, cb);
        const int g1 = NGRP * (CH / 256) * (HIDDEN / 256);
        gemm8_1<<<g1, 512, 131072, stream>>>(xb, W1t, b1, h, CH);
        dim3 g2((CH / 128) * (ABIN / 128), NGRP);
        gemm2<<<g2, 256, 0, stream>>>(h, W2t, b2, (float*)d_out, CH, cb);
    }
}

// Round 7
// 257.001 us; speedup vs baseline: 1.0096x; 1.0096x over previous
//
#include <hip/hip_runtime.h>
#include <stdint.h>

#define BTOT   4096
#define NGRP   8
#define DMODEL 1024
#define HIDDEN 2048
#define ABIN   256

typedef short bf16x8 __attribute__((ext_vector_type(8)));
typedef float f32x4  __attribute__((ext_vector_type(4)));

__device__ __forceinline__ ushort f2bf(float f) {
    union { float f; uint32_t u; } v; v.f = f;
    return (ushort)((v.u + 0x7FFFu + ((v.u >> 16) & 1u)) >> 16);
}

__device__ __forceinline__ void gl_lds16(const ushort* g, ushort* l) {
    __builtin_amdgcn_global_load_lds(
        (const __attribute__((address_space(1))) uint32_t*)g,
        (__attribute__((address_space(3))) uint32_t*)l,
        16, 0, 0);
}

// ---- W[n][K][N] f32 -> Wt[n][N][K] bf16 ----
__global__ void transpose_w(const float* __restrict__ W, ushort* __restrict__ Wt,
                            int K, int N)
{
    __shared__ float tl[32][33];
    const int n  = blockIdx.y;
    const int nt = blockIdx.x % (N / 32);
    const int kt = blockIdx.x / (N / 32);
    const float* Wn  = W  + (size_t)n * K * N;
    ushort*      Wtn = Wt + (size_t)n * N * K;
    const int tx = threadIdx.x & 31, ty = threadIdx.x >> 5;
#pragma unroll
    for (int j = 0; j < 4; j++)
        tl[ty + 8 * j][tx] = Wn[(size_t)(kt * 32 + ty + 8 * j) * N + nt * 32 + tx];
    __syncthreads();
#pragma unroll
    for (int j = 0; j < 4; j++) {
        const int r = ty + 8 * j;
        Wtn[(size_t)(nt * 32 + r) * K + kt * 32 + tx] = f2bf(tl[tx][r]);
    }
}

// ---- x[cb+r][n][d] f32 -> xb[n][r][d] bf16 ----
__global__ void conv_x(const float* __restrict__ x, ushort* __restrict__ xb,
                       int CH, int cb)
{
    const int flat = blockIdx.x * 256 + threadIdx.x;
    const int d8 = flat & 127;
    const int rem = flat >> 7;
    const int n = rem & 7;
    const int r = rem >> 3;
    const float* src = x + ((size_t)(cb + r) * NGRP + n) * DMODEL + d8 * 8;
    float4 v0 = *(const float4*)(src);
    float4 v1 = *(const float4*)(src + 4);
    bf16x8 p;
    p[0] = (short)f2bf(v0.x); p[1] = (short)f2bf(v0.y);
    p[2] = (short)f2bf(v0.z); p[3] = (short)f2bf(v0.w);
    p[4] = (short)f2bf(v1.x); p[5] = (short)f2bf(v1.y);
    p[6] = (short)f2bf(v1.z); p[7] = (short)f2bf(v1.w);
    *(bf16x8*)(xb + ((size_t)n * CH + r) * DMODEL + d8 * 8) = p;
}

// region(buf,op,half,ks): 128 rows x 32 k bf16 = 8 KiB, swizzled granules
#define REGN(buf,op,half,ks) (sm + ((((buf)*2+(op))*2+(half))*2+(ks))*4096)

template<int MH>
__device__ __forceinline__ void mma_q(f32x4 (&acc)[8][4], const bf16x8 (&af)[4],
                                      const bf16x8 (&bv)[4])
{
#pragma unroll
    for (int m4 = 0; m4 < 4; ++m4)
#pragma unroll
        for (int nf = 0; nf < 4; ++nf)
            acc[MH * 4 + m4][nf] = __builtin_amdgcn_mfma_f32_16x16x32_bf16(
                af[m4], bv[nf], acc[MH * 4 + m4][nf], 0, 0, 0);
}

// ---- 256x256 GEMM1: 4-phase tiles, all waits aged >= 1 phase ----
__global__ __launch_bounds__(512, 2)
void gemm8_1(const ushort* __restrict__ A, const ushort* __restrict__ Bt,
             const float* __restrict__ bias, ushort* __restrict__ h, int CH)
{
    constexpr int K = DMODEL, NDIM = HIDDEN, KT = K / 64;
    const int MT = CH >> 8, NT = NDIM >> 8;     // NT = 8
    extern __shared__ ushort sm[];

    // XCD-aware swizzle (nwg % 8 == 0 by construction)
    const int nwg = gridDim.x;
    const int bid = blockIdx.x;
    const int swz = (bid & 7) * (nwg >> 3) + (bid >> 3);
    const int n   = swz / (MT * NT);
    const int rem = swz - n * (MT * NT);
    const int mt  = rem / NT;
    const int nt  = rem - mt * NT;

    const int tid = threadIdx.x;
    const int l = tid & 63, wid = tid >> 6;
    const int wr = wid >> 2, wc = wid & 3, wc2 = wc >> 1;
    const int lq = l >> 4, lr = l & 15;

    const ushort* Ab = A  + ((size_t)n * CH   + (size_t)mt * 256) * K;
    const ushort* Bb = Bt + ((size_t)n * NDIM + (size_t)nt * 256) * K;

    // stage map: LDS linear granule tid holds global granule (srow, sseg)
    const int srow = tid >> 2;
    const int sseg = (tid & 3) ^ ((tid >> 3) & 3);

    auto stageA = [&](int b, int T, int ks) {
        const size_t kofs = (size_t)T * 64 + ks * 32 + sseg * 8;
        gl_lds16(Ab + (size_t)srow * K + kofs,         REGN(b, 0, 0, ks) + tid * 8);
        gl_lds16(Ab + (size_t)(128 + srow) * K + kofs, REGN(b, 0, 1, ks) + tid * 8);
    };
    auto stageB = [&](int b, int T, int ks) {
        const size_t kofs = (size_t)T * 64 + ks * 32 + sseg * 8;
        gl_lds16(Bb + (size_t)srow * K + kofs,         REGN(b, 1, 0, ks) + tid * 8);
        gl_lds16(Bb + (size_t)(128 + srow) * K + kofs, REGN(b, 1, 1, ks) + tid * 8);
    };
    auto ldA = [&](bf16x8 (&af)[4], int b, int kk, int mh) {
#pragma unroll
        for (int m4 = 0; m4 < 4; ++m4) {
            const int rh = mh * 64 + m4 * 16 + lr;
            af[m4] = *(const bf16x8*)(REGN(b, 0, wr, kk) + rh * 32 + (lq ^ ((rh >> 1) & 3)) * 8);
        }
    };
    auto ldB = [&](bf16x8 (&bv)[4], int b, int kk) {
#pragma unroll
        for (int nf = 0; nf < 4; ++nf) {
            const int rb = (wc & 1) * 64 + nf * 16 + lr;
            bv[nf] = *(const bf16x8*)(REGN(b, 1, wc2, kk) + rb * 32 + (lq ^ ((rb >> 1) & 3)) * 8);
        }
    };

    f32x4 acc[8][4];
#pragma unroll
    for (int i = 0; i < 8; ++i)
#pragma unroll
        for (int j = 0; j < 4; ++j) acc[i][j] = (f32x4){0.f, 0.f, 0.f, 0.f};

    // prologue: stage tile0 fully, drain, barrier, pre-issue P0's frags
    stageA(0, 0, 0); stageB(0, 0, 0);
    stageA(0, 0, 1); stageB(0, 0, 1);
    asm volatile("s_waitcnt vmcnt(0)" ::: "memory");
    __builtin_amdgcn_s_barrier();

    bf16x8 a0[4], a1[4], a2[4], a3[4], bE[4], bO[4];
    ldA(a0, 0, 0, 0); ldB(bE, 0, 0);        // 8 reads in flight

    for (int g = 0; g < KT; ++g) {
        const int c = g & 1;
        const bool ns = (g + 1 < KT);

        // P0: mma (kk0,mh0)=a0,bE; stage A(g+1) kk0+kk1; read a1
        if (ns) { stageA(c ^ 1, g + 1, 0); stageA(c ^ 1, g + 1, 1); }
        ldA(a1, c, 0, 1);
        asm volatile("s_waitcnt lgkmcnt(4)" ::: "memory");   // retire a0,bE (1 phase old)
        __builtin_amdgcn_sched_barrier(0);
        __builtin_amdgcn_s_setprio(1);
        mma_q<0>(acc, a0, bE);
        __builtin_amdgcn_s_setprio(0);
        __builtin_amdgcn_s_barrier();

        // P1: mma (kk0,mh1)=a1,bE; stage B(g+1) kk0+kk1; read a2,bO
        if (ns) { stageB(c ^ 1, g + 1, 0); stageB(c ^ 1, g + 1, 1); }
        ldA(a2, c, 1, 0); ldB(bO, c, 1);
        asm volatile("s_waitcnt lgkmcnt(8)" ::: "memory");   // retire a1 (1 phase old)
        __builtin_amdgcn_sched_barrier(0);
        __builtin_amdgcn_s_setprio(1);
        mma_q<1>(acc, a1, bE);
        __builtin_amdgcn_s_setprio(0);
        __builtin_amdgcn_s_barrier();

        // P2: mma (kk1,mh0)=a2,bO; read a3; GATE tile g+1 (ages 1-2 phases)
        ldA(a3, c, 1, 1);
        asm volatile("s_waitcnt lgkmcnt(4)" ::: "memory");   // retire a2,bO (1 phase old)
        __builtin_amdgcn_sched_barrier(0);
        __builtin_amdgcn_s_setprio(1);
        mma_q<0>(acc, a2, bO);
        __builtin_amdgcn_s_setprio(0);
        if (ns) asm volatile("s_waitcnt vmcnt(0)" ::: "memory");  // only g+1 stages in flight
        __builtin_amdgcn_s_barrier();

        // P3: mma (kk1,mh1)=a3,bO; cross-tile reads (post-gate, 1 phase ahead)
        if (ns) {
            ldA(a0, c ^ 1, 0, 0); ldB(bE, c ^ 1, 0);
            asm volatile("s_waitcnt lgkmcnt(8)" ::: "memory");   // retire a3
        } else {
            asm volatile("s_waitcnt lgkmcnt(0)" ::: "memory");
        }
        __builtin_amdgcn_sched_barrier(0);
        __builtin_amdgcn_s_setprio(1);
        mma_q<1>(acc, a3, bO);
        __builtin_amdgcn_s_setprio(0);
        __builtin_amdgcn_s_barrier();
    }

    __builtin_amdgcn_sched_barrier(0);

    // epilogue: bias + relu + bf16 store (row-contiguous 128 B segments)
    float bias4[4];
#pragma unroll
    for (int nf = 0; nf < 4; ++nf)
        bias4[nf] = bias[(size_t)n * NDIM + nt * 256 + wc * 64 + nf * 16 + lr];
#pragma unroll
    for (int m = 0; m < 8; ++m) {
#pragma unroll
        for (int r = 0; r < 4; ++r) {
            const int row = mt * 256 + wr * 128 + m * 16 + lq * 4 + r;
            ushort* dst = h + ((size_t)n * CH + row) * HIDDEN + nt * 256 + wc * 64 + lr;
#pragma unroll
            for (int nf = 0; nf < 4; ++nf)
                dst[nf * 16] = f2bf(fmaxf(acc[m][nf][r] + bias4[nf], 0.f));
        }
    }
}

// ---- GEMM2 (m97 128^2 structure, 2-way swizzled LDS): out = h @ W2t^T + b2 ----
__global__ __launch_bounds__(256, 2)
void gemm2(const ushort* __restrict__ A, const ushort* __restrict__ Bt,
           const float* __restrict__ bias, float* __restrict__ outp,
           int CH, int cb)
{
    constexpr int K = HIDDEN, NDIM = ABIN, NT = NDIM / 128, BK = 64;
    __shared__ __align__(16) ushort As[128 * BK];
    __shared__ __align__(16) ushort Bs[128 * BK];

    const int n  = blockIdx.y;
    const int mt = blockIdx.x / NT;
    const int nt = blockIdx.x % NT;

    const ushort* Ab = A  + ((size_t)n * CH   + mt * 128) * K;
    const ushort* Bb = Bt + ((size_t)n * NDIM + nt * 128) * K;

    const int t = threadIdx.x, l = t & 63, w = t >> 6;
    const int wr = w >> 1, wc = w & 1;
    const int lq = l >> 4, lr = l & 15;

    f32x4 acc[4][4];
#pragma unroll
    for (int i = 0; i < 4; i++)
#pragma unroll
        for (int j = 0; j < 4; j++) acc[i][j] = (f32x4){0.f, 0.f, 0.f, 0.f};

    for (int ki = 0; ki < K / BK; ++ki) {
        const ushort* Ak = Ab + ki * BK;
        const ushort* Bk = Bb + ki * BK;
        __syncthreads();
#pragma unroll
        for (int i = 0; i < 4; i++) {
            const int flat = t + 256 * i;
            const int row = flat >> 3;
            const int seg = (flat & 7) ^ (row & 7);     // both-sides swizzle
            gl_lds16(Ak + (size_t)row * K + seg * 8, (ushort*)As + flat * 8);
            gl_lds16(Bk + (size_t)row * K + seg * 8, (ushort*)Bs + flat * 8);
        }
        __syncthreads();

#pragma unroll
        for (int kk = 0; kk < 2; kk++) {
            bf16x8 af[4], bf[4];
#pragma unroll
            for (int m = 0; m < 4; m++) {
                const int row = wr * 64 + m * 16 + lr;
                af[m] = *(const bf16x8*)&As[row * BK + ((kk * 4 + lq) ^ (row & 7)) * 8];
            }
#pragma unroll
            for (int nf = 0; nf < 4; nf++) {
                const int row = wc * 64 + nf * 16 + lr;
                bf[nf] = *(const bf16x8*)&Bs[row * BK + ((kk * 4 + lq) ^ (row & 7)) * 8];
            }
#pragma unroll
            for (int m = 0; m < 4; m++)
#pragma unroll
                for (int nf = 0; nf < 4; nf++)
                    acc[m][nf] = __builtin_amdgcn_mfma_f32_16x16x32_bf16(af[m], bf[nf], acc[m][nf], 0, 0, 0);
        }
    }

#pragma unroll
    for (int nf = 0; nf < 4; nf++) {
        const int colg = nt * 128 + wc * 64 + nf * 16 + lr;
        const float bv = bias[(size_t)n * NDIM + colg];
#pragma unroll
        for (int m = 0; m < 4; m++) {
#pragma unroll
            for (int r = 0; r < 4; r++) {
                const int row = mt * 128 + wr * 64 + m * 16 + lq * 4 + r;
                outp[((size_t)(cb + row) * NGRP + n) * ABIN + colg] = acc[m][nf][r] + bv;
            }
        }
    }
}

extern "C" void kernel_launch(void* const* d_in, const int* in_sizes, int n_in,
                              void* d_out, int out_size, void* d_ws, size_t ws_size,
                              hipStream_t stream)
{
    const float* x  = (const float*)d_in[0];
    const float* W1 = (const float*)d_in[1];
    const float* b1 = (const float*)d_in[2];
    const float* W2 = (const float*)d_in[3];
    const float* b2 = (const float*)d_in[4];

    hipFuncSetAttribute((const void*)gemm8_1,
                        hipFuncAttributeMaxDynamicSharedMemorySize, 131072);

    ushort* W1t = (ushort*)d_ws;                              // [8][2048][1024]
    ushort* W2t = W1t + (size_t)NGRP * HIDDEN * DMODEL;       // [8][256][2048]
    ushort* xb  = W2t + (size_t)NGRP * ABIN * HIDDEN;
    const size_t fixed = ((size_t)NGRP * HIDDEN * DMODEL + (size_t)NGRP * ABIN * HIDDEN) * 2;

    int CH = 4096;
    while (CH > 256 && fixed + (size_t)CH * (NGRP * (DMODEL + HIDDEN) * 2) > ws_size) CH >>= 1;
    ushort* h = xb + (size_t)NGRP * CH * DMODEL;

    {
        dim3 g1((DMODEL / 32) * (HIDDEN / 32), NGRP);
        transpose_w<<<g1, 256, 0, stream>>>(W1, W1t, DMODEL, HIDDEN);
        dim3 g2((HIDDEN / 32) * (ABIN / 32), NGRP);
        transpose_w<<<g2, 256, 0, stream>>>(W2, W2t, HIDDEN, ABIN);
    }

    for (int cb = 0; cb < BTOT; cb += CH) {
        conv_x<<<CH * 4, 256, 0, stream>>>(x, xb, CH, cb);
        const int g1 = NGRP * (CH / 256) * (HIDDEN / 256);
        gemm8_1<<<g1, 512, 131072, stream>>>(xb, W1t, b1, h, CH);
        dim3 g2((CH / 128) * (ABIN / 128), NGRP);
        gemm2<<<g2, 256, 0, stream>>>(h, W2t, b2, (float*)d_out, CH, cb);
    }
}

// Round 8
// 255.536 us; speedup vs baseline: 1.0154x; 1.0057x over previous
//
#include <hip/hip_runtime.h>
#include <stdint.h>

#define BTOT   4096
#define NGRP   8
#define DMODEL 1024
#define HIDDEN 2048
#define ABIN   256

typedef short bf16x8 __attribute__((ext_vector_type(8)));
typedef float f32x4  __attribute__((ext_vector_type(4)));

__device__ __forceinline__ ushort f2bf(float f) {
    union { float f; uint32_t u; } v; v.f = f;
    return (ushort)((v.u + 0x7FFFu + ((v.u >> 16) & 1u)) >> 16);
}

__device__ __forceinline__ void gl_lds16(const ushort* g, ushort* l) {
    __builtin_amdgcn_global_load_lds(
        (const __attribute__((address_space(1))) uint32_t*)g,
        (__attribute__((address_space(3))) uint32_t*)l,
        16, 0, 0);
}

// ---- combined W1+W2 transpose: W[n][K][N] f32 -> Wt[n][N][K] bf16 ----
// blockIdx.x < W1_TILES handles W1, else W2 (saves one launch gap)
#define W1_TILES ((DMODEL / 32) * (HIDDEN / 32))
#define W2_TILES ((HIDDEN / 32) * (ABIN / 32))
__global__ void transpose_w12(const float* __restrict__ W1, ushort* __restrict__ W1t,
                              const float* __restrict__ W2, ushort* __restrict__ W2t)
{
    __shared__ float tl[32][33];
    const int n = blockIdx.y;
    const float* W; ushort* Wt; int K, N, bx;
    if (blockIdx.x < W1_TILES) {
        W = W1; Wt = W1t; K = DMODEL; N = HIDDEN; bx = blockIdx.x;
    } else {
        W = W2; Wt = W2t; K = HIDDEN; N = ABIN;  bx = blockIdx.x - W1_TILES;
    }
    const int nt = bx % (N / 32);
    const int kt = bx / (N / 32);
    const float* Wn  = W  + (size_t)n * K * N;
    ushort*      Wtn = Wt + (size_t)n * N * K;
    const int tx = threadIdx.x & 31, ty = threadIdx.x >> 5;
#pragma unroll
    for (int j = 0; j < 4; j++)
        tl[ty + 8 * j][tx] = Wn[(size_t)(kt * 32 + ty + 8 * j) * N + nt * 32 + tx];
    __syncthreads();
#pragma unroll
    for (int j = 0; j < 4; j++) {
        const int r = ty + 8 * j;
        Wtn[(size_t)(nt * 32 + r) * K + kt * 32 + tx] = f2bf(tl[tx][r]);
    }
}

// ---- x[cb+r][n][d] f32 -> xb[n][r][d] bf16 ----
__global__ void conv_x(const float* __restrict__ x, ushort* __restrict__ xb,
                       int CH, int cb)
{
    const int flat = blockIdx.x * 256 + threadIdx.x;
    const int d8 = flat & 127;
    const int rem = flat >> 7;
    const int n = rem & 7;
    const int r = rem >> 3;
    const float* src = x + ((size_t)(cb + r) * NGRP + n) * DMODEL + d8 * 8;
    float4 v0 = *(const float4*)(src);
    float4 v1 = *(const float4*)(src + 4);
    bf16x8 p;
    p[0] = (short)f2bf(v0.x); p[1] = (short)f2bf(v0.y);
    p[2] = (short)f2bf(v0.z); p[3] = (short)f2bf(v0.w);
    p[4] = (short)f2bf(v1.x); p[5] = (short)f2bf(v1.y);
    p[6] = (short)f2bf(v1.z); p[7] = (short)f2bf(v1.w);
    *(bf16x8*)(xb + ((size_t)n * CH + r) * DMODEL + d8 * 8) = p;
}

// region(buf,op,half,ks): 128 rows x 32 k bf16 = 8 KiB, swizzled granules
#define REGN(buf,op,half,ks) (sm + ((((buf)*2+(op))*2+(half))*2+(ks))*4096)

template<int MH>
__device__ __forceinline__ void mma_q(f32x4 (&acc)[8][4], const bf16x8 (&af)[4],
                                      const bf16x8 (&bv)[4])
{
#pragma unroll
    for (int m4 = 0; m4 < 4; ++m4)
#pragma unroll
        for (int nf = 0; nf < 4; ++nf)
            acc[MH * 4 + m4][nf] = __builtin_amdgcn_mfma_f32_16x16x32_bf16(
                af[m4], bv[nf], acc[MH * 4 + m4][nf], 0, 0, 0);
}

// ---- 256x256 8-phase GEMM1 with 1-deep fragment pipeline (R4 schedule) ----
__global__ __launch_bounds__(512, 2)
void gemm8_1(const ushort* __restrict__ A, const ushort* __restrict__ Bt,
             const float* __restrict__ bias, ushort* __restrict__ h, int CH)
{
    constexpr int K = DMODEL, NDIM = HIDDEN, KT = K / 64;
    const int MT = CH >> 8, NT = NDIM >> 8;     // NT = 8
    extern __shared__ ushort sm[];

    // XCD-aware swizzle (nwg % 8 == 0 by construction)
    const int nwg = gridDim.x;
    const int bid = blockIdx.x;
    const int swz = (bid & 7) * (nwg >> 3) + (bid >> 3);
    const int n   = swz / (MT * NT);
    const int rem = swz - n * (MT * NT);
    const int mt  = rem / NT;
    const int nt  = rem - mt * NT;

    const int tid = threadIdx.x;
    const int l = tid & 63, wid = tid >> 6;
    const int wr = wid >> 2, wc = wid & 3, wc2 = wc >> 1;
    const int lq = l >> 4, lr = l & 15;

    const ushort* Ab = A  + ((size_t)n * CH   + (size_t)mt * 256) * K;
    const ushort* Bb = Bt + ((size_t)n * NDIM + (size_t)nt * 256) * K;

    // stage map: LDS linear granule tid holds global granule (srow, sseg)
    const int srow = tid >> 2;
    const int sseg = (tid & 3) ^ ((tid >> 3) & 3);

    auto stageA = [&](int b, int T, int ks) {
        const size_t kofs = (size_t)T * 64 + ks * 32 + sseg * 8;
        gl_lds16(Ab + (size_t)srow * K + kofs,         REGN(b, 0, 0, ks) + tid * 8);
        gl_lds16(Ab + (size_t)(128 + srow) * K + kofs, REGN(b, 0, 1, ks) + tid * 8);
    };
    auto stageB = [&](int b, int T, int ks) {
        const size_t kofs = (size_t)T * 64 + ks * 32 + sseg * 8;
        gl_lds16(Bb + (size_t)srow * K + kofs,         REGN(b, 1, 0, ks) + tid * 8);
        gl_lds16(Bb + (size_t)(128 + srow) * K + kofs, REGN(b, 1, 1, ks) + tid * 8);
    };
    auto ldA = [&](bf16x8 (&af)[4], int b, int kk, int mh) {
#pragma unroll
        for (int m4 = 0; m4 < 4; ++m4) {
            const int rh = mh * 64 + m4 * 16 + lr;
            af[m4] = *(const bf16x8*)(REGN(b, 0, wr, kk) + rh * 32 + (lq ^ ((rh >> 1) & 3)) * 8);
        }
    };
    auto ldB = [&](bf16x8 (&bv)[4], int b, int kk) {
#pragma unroll
        for (int nf = 0; nf < 4; ++nf) {
            const int rb = (wc & 1) * 64 + nf * 16 + lr;
            bv[nf] = *(const bf16x8*)(REGN(b, 1, wc2, kk) + rb * 32 + (lq ^ ((rb >> 1) & 3)) * 8);
        }
    };

    f32x4 acc[8][4];
#pragma unroll
    for (int i = 0; i < 8; ++i)
#pragma unroll
        for (int j = 0; j < 4; ++j) acc[i][j] = (f32x4){0.f, 0.f, 0.f, 0.f};

    // prologue: stage tile 0, wait k0-half, barrier, prefetch P1 frags
    stageA(0, 0, 0); stageB(0, 0, 0); stageA(0, 0, 1); stageB(0, 0, 1);
    asm volatile("s_waitcnt vmcnt(4)" ::: "memory");
    __builtin_amdgcn_s_barrier();

    bf16x8 aX[4], aY[4], bv0[4], bv1[4];
    ldA(aX, 0, 0, 0); ldB(bv0, 0, 0);          // 8 reads in flight

    for (int g = 0; g < KT; ++g) {
        const int c = g & 1;
        const bool ns = (g + 1 < KT);

        // P1: mma (kk0,mh0) on aX,bv0; prefetch aY=(kk0,mh1); gate kk1(g)
        ldA(aY, c, 0, 1);
        if (ns) stageA(c ^ 1, g + 1, 0);
        asm volatile("s_waitcnt lgkmcnt(4)" ::: "memory");
        __builtin_amdgcn_sched_barrier(0);
        __builtin_amdgcn_s_setprio(1);
        mma_q<0>(acc, aX, bv0);
        __builtin_amdgcn_s_setprio(0);
        if (ns) asm volatile("s_waitcnt vmcnt(2)" ::: "memory");
        else    asm volatile("s_waitcnt vmcnt(0)" ::: "memory");
        __builtin_amdgcn_s_barrier();

        // P2: mma (kk0,mh1) on aY,bv0; prefetch aX=(kk1,mh0), bv1=(kk1)
        ldA(aX, c, 1, 0); ldB(bv1, c, 1);
        if (ns) stageB(c ^ 1, g + 1, 0);
        asm volatile("s_waitcnt lgkmcnt(8)" ::: "memory");
        __builtin_amdgcn_sched_barrier(0);
        __builtin_amdgcn_s_setprio(1);
        mma_q<1>(acc, aY, bv0);
        __builtin_amdgcn_s_setprio(0);
        __builtin_amdgcn_s_barrier();

        // P3: mma (kk1,mh0) on aX,bv1; prefetch aY=(kk1,mh1)
        ldA(aY, c, 1, 1);
        if (ns) stageA(c ^ 1, g + 1, 1);
        asm volatile("s_waitcnt lgkmcnt(4)" ::: "memory");
        __builtin_amdgcn_sched_barrier(0);
        __builtin_amdgcn_s_setprio(1);
        mma_q<0>(acc, aX, bv1);
        __builtin_amdgcn_s_setprio(0);
        __builtin_amdgcn_s_barrier();

        // P4: mma (kk1,mh1) on aY,bv1; gate kk0(g+1); cross-tile prefetch after
        if (ns) stageB(c ^ 1, g + 1, 1);
        asm volatile("s_waitcnt lgkmcnt(0)" ::: "memory");
        __builtin_amdgcn_sched_barrier(0);
        __builtin_amdgcn_s_setprio(1);
        mma_q<1>(acc, aY, bv1);
        __builtin_amdgcn_s_setprio(0);
        if (ns) asm volatile("s_waitcnt vmcnt(4)" ::: "memory");
        __builtin_amdgcn_s_barrier();
        if (ns) { ldA(aX, c ^ 1, 0, 0); ldB(bv0, c ^ 1, 0); }
    }

    __builtin_amdgcn_sched_barrier(0);

    // epilogue: bias + relu + bf16 store (row-contiguous 128 B segments)
    float bias4[4];
#pragma unroll
    for (int nf = 0; nf < 4; ++nf)
        bias4[nf] = bias[(size_t)n * NDIM + nt * 256 + wc * 64 + nf * 16 + lr];
#pragma unroll
    for (int m = 0; m < 8; ++m) {
#pragma unroll
        for (int r = 0; r < 4; ++r) {
            const int row = mt * 256 + wr * 128 + m * 16 + lq * 4 + r;
            ushort* dst = h + ((size_t)n * CH + row) * HIDDEN + nt * 256 + wc * 64 + lr;
#pragma unroll
            for (int nf = 0; nf < 4; ++nf)
                dst[nf * 16] = f2bf(fmaxf(acc[m][nf][r] + bias4[nf], 0.f));
        }
    }
}

// ---- GEMM2 (m97 128^2, swizzled LDS, 4 blocks/CU): out = h @ W2t^T + b2 ----
__global__ __launch_bounds__(256, 4)
void gemm2(const ushort* __restrict__ A, const ushort* __restrict__ Bt,
           const float* __restrict__ bias, float* __restrict__ outp,
           int CH, int cb)
{
    constexpr int K = HIDDEN, NDIM = ABIN, NT = NDIM / 128, BK = 64;
    __shared__ __align__(16) ushort As[128 * BK];
    __shared__ __align__(16) ushort Bs[128 * BK];

    const int n  = blockIdx.y;
    const int mt = blockIdx.x / NT;
    const int nt = blockIdx.x % NT;

    const ushort* Ab = A  + ((size_t)n * CH   + mt * 128) * K;
    const ushort* Bb = Bt + ((size_t)n * NDIM + nt * 128) * K;

    const int t = threadIdx.x, l = t & 63, w = t >> 6;
    const int wr = w >> 1, wc = w & 1;
    const int lq = l >> 4, lr = l & 15;

    f32x4 acc[4][4];
#pragma unroll
    for (int i = 0; i < 4; i++)
#pragma unroll
        for (int j = 0; j < 4; j++) acc[i][j] = (f32x4){0.f, 0.f, 0.f, 0.f};

    for (int ki = 0; ki < K / BK; ++ki) {
        const ushort* Ak = Ab + ki * BK;
        const ushort* Bk = Bb + ki * BK;
        __syncthreads();
#pragma unroll
        for (int i = 0; i < 4; i++) {
            const int flat = t + 256 * i;
            const int row = flat >> 3;
            const int seg = (flat & 7) ^ (row & 7);     // both-sides swizzle
            gl_lds16(Ak + (size_t)row * K + seg * 8, (ushort*)As + flat * 8);
            gl_lds16(Bk + (size_t)row * K + seg * 8, (ushort*)Bs + flat * 8);
        }
        __syncthreads();

#pragma unroll
        for (int kk = 0; kk < 2; kk++) {
            bf16x8 af[4], bf[4];
#pragma unroll
            for (int m = 0; m < 4; m++) {
                const int row = wr * 64 + m * 16 + lr;
                af[m] = *(const bf16x8*)&As[row * BK + ((kk * 4 + lq) ^ (row & 7)) * 8];
            }
#pragma unroll
            for (int nf = 0; nf < 4; nf++) {
                const int row = wc * 64 + nf * 16 + lr;
                bf[nf] = *(const bf16x8*)&Bs[row * BK + ((kk * 4 + lq) ^ (row & 7)) * 8];
            }
#pragma unroll
            for (int m = 0; m < 4; m++)
#pragma unroll
                for (int nf = 0; nf < 4; nf++)
                    acc[m][nf] = __builtin_amdgcn_mfma_f32_16x16x32_bf16(af[m], bf[nf], acc[m][nf], 0, 0, 0);
        }
    }

#pragma unroll
    for (int nf = 0; nf < 4; nf++) {
        const int colg = nt * 128 + wc * 64 + nf * 16 + lr;
        const float bv = bias[(size_t)n * NDIM + colg];
#pragma unroll
        for (int m = 0; m < 4; m++) {
#pragma unroll
            for (int r = 0; r < 4; r++) {
                const int row = mt * 128 + wr * 64 + m * 16 + lq * 4 + r;
                outp[((size_t)(cb + row) * NGRP + n) * ABIN + colg] = acc[m][nf][r] + bv;
            }
        }
    }
}

extern "C" void kernel_launch(void* const* d_in, const int* in_sizes, int n_in,
                              void* d_out, int out_size, void* d_ws, size_t ws_size,
                              hipStream_t stream)
{
    const float* x  = (const float*)d_in[0];
    const float* W1 = (const float*)d_in[1];
    const float* b1 = (const float*)d_in[2];
    const float* W2 = (const float*)d_in[3];
    const float* b2 = (const float*)d_in[4];

    hipFuncSetAttribute((const void*)gemm8_1,
                        hipFuncAttributeMaxDynamicSharedMemorySize, 131072);

    ushort* W1t = (ushort*)d_ws;                              // [8][2048][1024]
    ushort* W2t = W1t + (size_t)NGRP * HIDDEN * DMODEL;       // [8][256][2048]
    ushort* xb  = W2t + (size_t)NGRP * ABIN * HIDDEN;
    const size_t fixed = ((size_t)NGRP * HIDDEN * DMODEL + (size_t)NGRP * ABIN * HIDDEN) * 2;

    int CH = 4096;
    while (CH > 256 && fixed + (size_t)CH * (NGRP * (DMODEL + HIDDEN) * 2) > ws_size) CH >>= 1;
    ushort* h = xb + (size_t)NGRP * CH * DMODEL;

    {
        dim3 g(W1_TILES + W2_TILES, NGRP);
        transpose_w12<<<g, 256, 0, stream>>>(W1, W1t, W2, W2t);
    }

    for (int cb = 0; cb < BTOT; cb += CH) {
        conv_x<<<CH * 4, 256, 0, stream>>>(x, xb, CH, cb);
        const int g1 = NGRP * (CH / 256) * (HIDDEN / 256);
        gemm8_1<<<g1, 512, 131072, stream>>>(xb, W1t, b1, h, CH);
        dim3 g2((CH / 128) * (ABIN / 128), NGRP);
        gemm2<<<g2, 256, 0, stream>>>(h, W2t, b2, (float*)d_out, CH, cb);
    }
}